// Round 5
// baseline (241.441 us; speedup 1.0000x reference)
//
#include <hip/hip_runtime.h>

#define NN 50000
#define NE 500000
#define DD 128
#define NTILE 782            // ceil(NN/64)
#define NBLK (3 * NTILE)     // transform blocks (3 segs)
#define EPB 214              // ceil(NE / NBLK) hist edges per transform block
#define OFFS_PAD 50176       // 49*1024, >= NN+1

// ALPHA = 0.5 → both sqrt(ALPHA) and sqrt(1-ALPHA) are sqrt(0.5).
__device__ __constant__ float SQ_A = 0.70710678118654752440f;

typedef __attribute__((ext_vector_type(8))) short short8;
typedef __attribute__((ext_vector_type(4))) float float4v;

// float → bf16 bits, round-to-nearest-even.
__device__ inline ushort f2bf(float f)
{
    uint u = __float_as_uint(f);
    u += 0x7fffu + ((u >> 16) & 1u);
    return (ushort)(u >> 16);
}
__device__ inline uint pk2(float a, float b)
{
    return (uint)f2bf(a) | ((uint)f2bf(b) << 16);
}
__device__ inline float bf_lo(uint d) { return __uint_as_float(d << 16); }
__device__ inline float bf_hi(uint d) { return __uint_as_float(d & 0xffff0000u); }

// ---------------------------------------------------------------------------
// Prep (tiny): W/loop_w → wtb bf16 transposed+scaled [3][col=128][k=128];
// zero offs[OFFS_PAD]. 74 blocks.
// ---------------------------------------------------------------------------
#define PREP_WTB  (3 * 2048)         // per seg: 16 k-chunks * 128 cols
#define PREP_ZERO (OFFS_PAD / 4)
#define PREP_TASKS (PREP_WTB + PREP_ZERO)

__global__ __launch_bounds__(256)
void prep_kernel(const float* __restrict__ weight,
                 const float* __restrict__ loop_w,
                 ushort* __restrict__ wtb,
                 int* __restrict__ offs)
{
    int t = blockIdx.x * 256 + threadIdx.x;
    if (t < PREP_WTB) {
        int seg = t >> 11;           // 0,1 → relations; 2 → loop
        int c   = (t >> 7) & 15;     // k-chunk
        int col = t & 127;           // lanes consecutive in col → coalesced
        const float* wsrc = (seg < 2) ? (weight + (size_t)seg * DD * DD)
                                      : loop_w;
        float v[8];
#pragma unroll
        for (int j = 0; j < 8; ++j)
            v[j] = wsrc[(size_t)(c * 8 + j) * DD + col] * SQ_A;
        uint4 pk;
        pk.x = pk2(v[0], v[1]); pk.y = pk2(v[2], v[3]);
        pk.z = pk2(v[4], v[5]); pk.w = pk2(v[6], v[7]);
        *(uint4*)&wtb[((size_t)seg * DD + col) * DD + c * 8] = pk;
    } else if (t < PREP_TASKS) {
        int u = t - PREP_WTB;
        ((int4*)offs)[u] = make_int4(0, 0, 0, 0);
    }
}

// ---------------------------------------------------------------------------
// Transform + folded histogram. Grid (3, NTILE): seg = blockIdx.x (fastest →
// 3 same-tile blocks adjacent → feat rows L2-hot), tile = blockIdx.y.
// LDS-free MFMA: A-frags packed fp32→bf16 in registers from feat; B-frags
// (8×b128) preloaded from wtb. Each block also atomics EPB edges into offs
// (histogram), fully overlapped with the MFMA work.
//   seg 0/1 → hrelb[r] (bf16, sqrt(a) folded into wtb)
//   seg 2   → out = bias + loop message (fp32)
// ---------------------------------------------------------------------------
__global__ __launch_bounds__(256)
void transform_mfma_kernel(const float* __restrict__ feat,
                           const ushort* __restrict__ wtb,
                           const float* __restrict__ h_bias,
                           const int* __restrict__ dst,
                           int* __restrict__ offs,
                           ushort* __restrict__ hrelb,
                           float* __restrict__ out)
{
    const int seg  = blockIdx.x;
    const int tile = blockIdx.y;

    // Folded histogram slice (no barrier needed; independent of MFMA work).
    {
        int e = (seg * NTILE + tile) * EPB + threadIdx.x;
        if (threadIdx.x < EPB && e < NE) atomicAdd(&offs[dst[e]], 1);
    }

    const int node0 = tile * 64;
    const int wv    = threadIdx.x >> 6;
    const int lane  = threadIdx.x & 63;
    const int mq    = lane & 15;
    const int quad  = lane >> 4;
    const int col0  = wv * 32;

    const ushort* wseg = wtb + (size_t)seg * DD * DD;

    // Preload B fragments: B[n=mq][k=quad*8+j] per (nt, ks).
    short8 bfrag[2][4];
#pragma unroll
    for (int nt = 0; nt < 2; ++nt)
#pragma unroll
        for (int ks = 0; ks < 4; ++ks)
            bfrag[nt][ks] = *(const short8*)
                &wseg[(size_t)(col0 + nt * 16 + mq) * DD + ks * 32 + quad * 8];

    float4v acc[4][2];
#pragma unroll
    for (int mt = 0; mt < 4; ++mt)
#pragma unroll
        for (int nt = 0; nt < 2; ++nt)
            acc[mt][nt] = (float4v){0.f, 0.f, 0.f, 0.f};

#pragma unroll
    for (int mt = 0; mt < 4; ++mt) {
        const int row = node0 + mt * 16 + mq;
        const bool ok = (row < NN);
        const float4* fp = (const float4*)(feat + (size_t)row * DD);
#pragma unroll
        for (int ks = 0; ks < 4; ++ks) {
            float4 v0 = make_float4(0.f, 0.f, 0.f, 0.f), v1 = v0;
            if (ok) {
                v0 = fp[ks * 8 + quad * 2];
                v1 = fp[ks * 8 + quad * 2 + 1];
            }
            uint4 pk;
            pk.x = pk2(v0.x, v0.y); pk.y = pk2(v0.z, v0.w);
            pk.z = pk2(v1.x, v1.y); pk.w = pk2(v1.z, v1.w);
            short8 a = *(short8*)&pk;
#pragma unroll
            for (int nt = 0; nt < 2; ++nt)
                acc[mt][nt] = __builtin_amdgcn_mfma_f32_16x16x32_bf16(
                    a, bfrag[nt][ks], acc[mt][nt], 0, 0, 0);
        }
    }

    // Epilogue. D: row = quad*4 + r, col = mq (per 16x16 tile).
    if (seg < 2) {
        ushort* hb = hrelb + (size_t)seg * NN * DD;
#pragma unroll
        for (int mt = 0; mt < 4; ++mt) {
#pragma unroll
            for (int r = 0; r < 4; ++r) {
                int node = node0 + mt * 16 + quad * 4 + r;
                if (node < NN) {
#pragma unroll
                    for (int nt = 0; nt < 2; ++nt)
                        hb[(size_t)node * DD + col0 + nt * 16 + mq] =
                            f2bf(acc[mt][nt][r]);
                }
            }
        }
    } else {
        float b0 = h_bias[col0 + mq];
        float b1 = h_bias[col0 + 16 + mq];
#pragma unroll
        for (int mt = 0; mt < 4; ++mt) {
#pragma unroll
            for (int r = 0; r < 4; ++r) {
                int node = node0 + mt * 16 + quad * 4 + r;
                if (node < NN) {
                    out[(size_t)node * DD + col0 + mq]      = acc[mt][0][r] + b0;
                    out[(size_t)node * DD + col0 + 16 + mq] = acc[mt][1][r] + b1;
                }
            }
        }
    }
}

// ---------------------------------------------------------------------------
// Fused exclusive scan of offs[0..OFFS_PAD) in ONE block (1024 threads,
// 49 rounds). Carry kept in registers (identical in all threads). Also
// writes cursor[i] = excl for i < NN.
// ---------------------------------------------------------------------------
__global__ __launch_bounds__(1024)
void scan_kernel(int* __restrict__ offs, int* __restrict__ cursor)
{
    __shared__ int ws[2][16];
    const int lane = threadIdx.x & 63;
    const int wvi  = threadIdx.x >> 6;
    int carry = 0;
    for (int r = 0; r < 49; ++r) {
        int i = r * 1024 + threadIdx.x;
        int v = offs[i];
        int inc = v;
#pragma unroll
        for (int d = 1; d < 64; d <<= 1) {
            int t = __shfl_up(inc, d, 64);
            if (lane >= d) inc += t;
        }
        if (lane == 63) ws[r & 1][wvi] = inc;
        __syncthreads();
        int wbase = 0, total = 0;
#pragma unroll
        for (int w = 0; w < 16; ++w) {
            int s = ws[r & 1][w];
            total += s;
            if (w < wvi) wbase += s;
        }
        int excl = carry + wbase + inc - v;
        offs[i] = excl;                 // i == NN gets total (=NE) ✓
        if (i < NN) cursor[i] = excl;
        carry += total;
    }
}

__global__ __launch_bounds__(256)
void place_kernel(const int* __restrict__ src, const int* __restrict__ dst,
                  const int* __restrict__ ety,
                  int* __restrict__ cursor, int* __restrict__ payload)
{
    int e = blockIdx.x * 256 + threadIdx.x;
    if (e >= NE) return;
    int p = atomicAdd(&cursor[dst[e]], 1);
    payload[p] = (ety[e] << 16) | src[e];
}

// ---------------------------------------------------------------------------
// Gather: one wave per node; bf16 messages, fp32 accumulate, 4 loads in
// flight. acc starts at out[n] (= bias + loop message).
// ---------------------------------------------------------------------------
__global__ __launch_bounds__(256)
void gather_kernel(const int* __restrict__ offs, const int* __restrict__ payload,
                   const ushort* __restrict__ hrelb, float* __restrict__ out)
{
    const int n = blockIdx.x * 4 + (threadIdx.x >> 6);
    if (n >= NN) return;
    const int lane = threadIdx.x & 63;
    const int e0 = offs[n];
    const int e1 = offs[n + 1];
    float* orow = out + (size_t)n * DD;
    float2 a0 = ((float2*)orow)[lane];
    float2 a1 = make_float2(0.f, 0.f);
    float2 a2 = make_float2(0.f, 0.f);
    float2 a3 = make_float2(0.f, 0.f);
    int e = e0;
    for (; e + 4 <= e1; e += 4) {
        int p0 = payload[e],     p1 = payload[e + 1];
        int p2 = payload[e + 2], p3 = payload[e + 3];
        uint d0 = *(const uint*)&hrelb[
            ((size_t)(p0 >> 16) * NN + (p0 & 0xffff)) * DD + lane * 2];
        uint d1 = *(const uint*)&hrelb[
            ((size_t)(p1 >> 16) * NN + (p1 & 0xffff)) * DD + lane * 2];
        uint d2 = *(const uint*)&hrelb[
            ((size_t)(p2 >> 16) * NN + (p2 & 0xffff)) * DD + lane * 2];
        uint d3 = *(const uint*)&hrelb[
            ((size_t)(p3 >> 16) * NN + (p3 & 0xffff)) * DD + lane * 2];
        a0.x += bf_lo(d0); a0.y += bf_hi(d0);
        a1.x += bf_lo(d1); a1.y += bf_hi(d1);
        a2.x += bf_lo(d2); a2.y += bf_hi(d2);
        a3.x += bf_lo(d3); a3.y += bf_hi(d3);
    }
    for (; e < e1; ++e) {
        int p0 = payload[e];
        uint d0 = *(const uint*)&hrelb[
            ((size_t)(p0 >> 16) * NN + (p0 & 0xffff)) * DD + lane * 2];
        a0.x += bf_lo(d0); a0.y += bf_hi(d0);
    }
    a0.x += a1.x + a2.x + a3.x;
    a0.y += a1.y + a2.y + a3.y;
    ((float2*)orow)[lane] = a0;
}

// ---------------------------------------------------------------------------
// Tier-2 fallback: atomic scatter from bf16 hrelb.
// ---------------------------------------------------------------------------
__global__ __launch_bounds__(256)
void scatter_kernel(const int* __restrict__ src, const int* __restrict__ dst,
                    const int* __restrict__ ety,
                    const ushort* __restrict__ hrelb,
                    float* __restrict__ out)
{
    const int e = blockIdx.x * 4 + (threadIdx.x >> 6);
    if (e >= NE) return;
    const int lane = threadIdx.x & 63;
    uint d0 = *(const uint*)&hrelb[
        ((size_t)ety[e] * NN + src[e]) * DD + lane * 2];
    float* o = out + (size_t)dst[e] * DD + lane * 2;
    atomicAdd(o,     bf_lo(d0));
    atomicAdd(o + 1, bf_hi(d0));
}

// Tier-3 fallback: fp32 out-init (loop message + bias) + fused per-edge matvec.
__global__ __launch_bounds__(256)
void loop_init_kernel(const float* __restrict__ feat,
                      const float* __restrict__ loop_weight,
                      const float* __restrict__ h_bias,
                      float* __restrict__ out)
{
    const int n = blockIdx.x * 4 + (threadIdx.x >> 6);
    if (n >= NN) return;
    const int lane = threadIdx.x & 63;
    const float2 fv = ((const float2*)(feat + (size_t)n * DD))[lane];
    float a0 = h_bias[lane], a1 = h_bias[lane + 64];
    for (int k = 0; k < 64; ++k) {
        float f0 = __shfl(fv.x, k, 64);
        float f1 = __shfl(fv.y, k, 64);
        a0 += SQ_A * (f0 * loop_weight[(size_t)(2 * k) * DD + lane]
                    + f1 * loop_weight[(size_t)(2 * k + 1) * DD + lane]);
        a1 += SQ_A * (f0 * loop_weight[(size_t)(2 * k) * DD + lane + 64]
                    + f1 * loop_weight[(size_t)(2 * k + 1) * DD + lane + 64]);
    }
    out[(size_t)n * DD + lane] = a0;
    out[(size_t)n * DD + lane + 64] = a1;
}

__global__ __launch_bounds__(256)
void fused_edge_kernel(const float* __restrict__ feat,
                       const int* __restrict__ src, const int* __restrict__ dst,
                       const int* __restrict__ ety,
                       const float* __restrict__ weight,
                       float* __restrict__ out)
{
    const int wave  = threadIdx.x >> 6;
    const int lane  = threadIdx.x & 63;
    const int nwav  = gridDim.x * 4;
    for (int e = blockIdx.x * 4 + wave; e < NE; e += nwav) {
        const int s = src[e];
        const int d = dst[e];
        const int r = ety[e];
        const float2 fv = ((const float2*)(feat + (size_t)s * DD))[lane];
        const float* W = weight + (size_t)r * DD * DD;
        float a0 = 0.f, a1 = 0.f;
        for (int k = 0; k < 64; ++k) {
            float f0 = __shfl(fv.x, k, 64);
            float f1 = __shfl(fv.y, k, 64);
            a0 += f0 * W[(size_t)(2 * k) * DD + lane]
                + f1 * W[(size_t)(2 * k + 1) * DD + lane];
            a1 += f0 * W[(size_t)(2 * k) * DD + lane + 64]
                + f1 * W[(size_t)(2 * k + 1) * DD + lane + 64];
        }
        atomicAdd(out + (size_t)d * DD + lane,      SQ_A * a0);
        atomicAdd(out + (size_t)d * DD + lane + 64, SQ_A * a1);
    }
}

extern "C" void kernel_launch(void* const* d_in, const int* in_sizes, int n_in,
                              void* d_out, int out_size, void* d_ws, size_t ws_size,
                              hipStream_t stream)
{
    const float* feat   = (const float*)d_in[0];
    const int*   src    = (const int*)d_in[1];
    const int*   dst    = (const int*)d_in[2];
    const int*   ety    = (const int*)d_in[3];
    const float* weight = (const float*)d_in[4];
    const float* loop_w = (const float*)d_in[5];
    const float* h_bias = (const float*)d_in[6];
    float* out  = (float*)d_out;

    // Workspace layout (all sections 16B-multiple sized).
    char* p = (char*)d_ws;
    ushort* wtb   = (ushort*)p;  p += (size_t)3 * DD * DD * 2;  // 96 KB
    ushort* hrelb = (ushort*)p;  p += (size_t)2 * NN * DD * 2;  // 25.6 MB
    int* offs     = (int*)p;     p += (size_t)OFFS_PAD * 4;
    const size_t need_t2 = (size_t)(p - (char*)d_ws);
    int* cursor   = (int*)p;     p += (size_t)OFFS_PAD * 4;
    int* payload  = (int*)p;     p += (size_t)NE * 4;
    const size_t need_full = (size_t)(p - (char*)d_ws);         // ~28.5 MB

    if (ws_size >= need_full) {
        prep_kernel<<<(PREP_TASKS + 255) / 256, 256, 0, stream>>>(
            weight, loop_w, wtb, offs);
        transform_mfma_kernel<<<dim3(3, NTILE), 256, 0, stream>>>(
            feat, wtb, h_bias, dst, offs, hrelb, out);
        scan_kernel<<<1, 1024, 0, stream>>>(offs, cursor);
        place_kernel<<<(NE + 255) / 256, 256, 0, stream>>>(
            src, dst, ety, cursor, payload);
        gather_kernel<<<(NN + 3) / 4, 256, 0, stream>>>(
            offs, payload, hrelb, out);
    } else if (ws_size >= need_t2) {
        prep_kernel<<<(PREP_TASKS + 255) / 256, 256, 0, stream>>>(
            weight, loop_w, wtb, offs);
        transform_mfma_kernel<<<dim3(3, NTILE), 256, 0, stream>>>(
            feat, wtb, h_bias, dst, offs, hrelb, out);
        scatter_kernel<<<dim3((NE + 3) / 4), 256, 0, stream>>>(
            src, dst, ety, hrelb, out);
    } else {
        loop_init_kernel<<<(NN + 3) / 4, 256, 0, stream>>>(
            feat, loop_w, h_bias, out);
        fused_edge_kernel<<<dim3(2048), 256, 0, stream>>>(
            feat, src, dst, ety, weight, out);
    }
}

// Round 6
// 229.731 us; speedup vs baseline: 1.0510x; 1.0510x over previous
//
#include <hip/hip_runtime.h>

#define NN 50000
#define NPAD 50048           // 782 * 64 (featb rows, tail zeroed)
#define NE 500000
#define DD 128
#define NTILE 782            // ceil(NN/64)
#define EPB 214              // ceil(NE / (3*NTILE)) hist edges per transform block
#define OFFS_PAD 50176       // 49*1024, >= NN+1

// ALPHA = 0.5 → both sqrt(ALPHA) and sqrt(1-ALPHA) are sqrt(0.5).
__device__ __constant__ float SQ_A = 0.70710678118654752440f;

typedef __attribute__((ext_vector_type(8))) short short8;
typedef __attribute__((ext_vector_type(4))) float float4v;

// float → bf16 bits, round-to-nearest-even.
__device__ inline ushort f2bf(float f)
{
    uint u = __float_as_uint(f);
    u += 0x7fffu + ((u >> 16) & 1u);
    return (ushort)(u >> 16);
}
__device__ inline uint pk2(float a, float b)
{
    return (uint)f2bf(a) | ((uint)f2bf(b) << 16);
}
__device__ inline float bf_lo(uint d) { return __uint_as_float(d << 16); }
__device__ inline float bf_hi(uint d) { return __uint_as_float(d & 0xffff0000u); }

// ---------------------------------------------------------------------------
// Prep: feat fp32 → featb bf16 [NPAD][128] (rows >= NN zeroed);
//       W/loop_w → wtb bf16 transposed+scaled [3][col=128][k=128];
//       zero offs[OFFS_PAD].
// ---------------------------------------------------------------------------
#define PREP_FEAT (NPAD * 16)        // 16 chunks of 8 elems per row
#define PREP_WTB  (3 * 2048)         // per seg: 16 k-chunks * 128 cols
#define PREP_ZERO (OFFS_PAD / 4)
#define PREP_TASKS (PREP_FEAT + PREP_WTB + PREP_ZERO)

__global__ __launch_bounds__(256)
void prep_kernel(const float* __restrict__ feat,
                 const float* __restrict__ weight,
                 const float* __restrict__ loop_w,
                 ushort* __restrict__ featb,
                 ushort* __restrict__ wtb,
                 int* __restrict__ offs)
{
    int t = blockIdx.x * 256 + threadIdx.x;
    if (t < PREP_FEAT) {
        int row = t >> 4;
        int c   = t & 15;            // k-chunk: elems c*8 .. c*8+7
        float4 v0 = make_float4(0.f, 0.f, 0.f, 0.f), v1 = v0;
        if (row < NN) {
            const float4* p = (const float4*)(feat + (size_t)row * DD + c * 8);
            v0 = p[0]; v1 = p[1];
        }
        uint4 pk;
        pk.x = pk2(v0.x, v0.y); pk.y = pk2(v0.z, v0.w);
        pk.z = pk2(v1.x, v1.y); pk.w = pk2(v1.z, v1.w);
        *(uint4*)&featb[(size_t)row * DD + c * 8] = pk;
    } else if (t < PREP_FEAT + PREP_WTB) {
        int u   = t - PREP_FEAT;
        int seg = u >> 11;           // 0,1 → relations; 2 → loop
        int c   = (u >> 7) & 15;     // k-chunk
        int col = u & 127;           // lanes consecutive in col → coalesced
        const float* wsrc = (seg < 2) ? (weight + (size_t)seg * DD * DD)
                                      : loop_w;
        float v[8];
#pragma unroll
        for (int j = 0; j < 8; ++j)
            v[j] = wsrc[(size_t)(c * 8 + j) * DD + col] * SQ_A;
        uint4 pk;
        pk.x = pk2(v[0], v[1]); pk.y = pk2(v[2], v[3]);
        pk.z = pk2(v[4], v[5]); pk.w = pk2(v[6], v[7]);
        *(uint4*)&wtb[((size_t)seg * DD + col) * DD + c * 8] = pk;
    } else if (t < PREP_TASKS) {
        int u = t - (PREP_FEAT + PREP_WTB);
        ((int4*)offs)[u] = make_int4(0, 0, 0, 0);
    }
}

// ---------------------------------------------------------------------------
// Transform + folded histogram. Grid (3, NTILE): seg = blockIdx.x (fastest →
// the 3 same-tile blocks are dispatch-adjacent → featb tile L2-hot),
// tile = blockIdx.y.
// LDS-free MFMA: A-frags (short8) straight from featb (pre-converted bf16,
// padded rows → no bounds check); B-frags (8×b128) preloaded from wtb.
// Each block also histograms EPB edges into offs (offs zeroed in prep).
//   seg 0/1 → hrelb[r] (bf16, sqrt(a) folded into wtb)
//   seg 2   → out = bias + loop message (fp32)
// ---------------------------------------------------------------------------
__global__ __launch_bounds__(256)
void transform_mfma_kernel(const ushort* __restrict__ featb,
                           const ushort* __restrict__ wtb,
                           const float* __restrict__ h_bias,
                           const int* __restrict__ dst,
                           int* __restrict__ offs,
                           ushort* __restrict__ hrelb,
                           float* __restrict__ out)
{
    const int seg  = blockIdx.x;
    const int tile = blockIdx.y;

    // Folded histogram slice (independent of the MFMA work; no barrier).
    {
        int e = (seg * NTILE + tile) * EPB + threadIdx.x;
        if (threadIdx.x < EPB && e < NE) atomicAdd(&offs[dst[e]], 1);
    }

    const int node0 = tile * 64;
    const int wv    = threadIdx.x >> 6;
    const int lane  = threadIdx.x & 63;
    const int mq    = lane & 15;
    const int quad  = lane >> 4;
    const int col0  = wv * 32;

    const ushort* wseg = wtb + (size_t)seg * DD * DD;

    // Preload B fragments: B[n=mq][k=quad*8+j] per (nt, ks).
    short8 bfrag[2][4];
#pragma unroll
    for (int nt = 0; nt < 2; ++nt)
#pragma unroll
        for (int ks = 0; ks < 4; ++ks)
            bfrag[nt][ks] = *(const short8*)
                &wseg[(size_t)(col0 + nt * 16 + mq) * DD + ks * 32 + quad * 8];

    float4v acc[4][2];
#pragma unroll
    for (int mt = 0; mt < 4; ++mt)
#pragma unroll
        for (int nt = 0; nt < 2; ++nt)
            acc[mt][nt] = (float4v){0.f, 0.f, 0.f, 0.f};

#pragma unroll
    for (int mt = 0; mt < 4; ++mt) {
        const ushort* arow = featb + (size_t)(node0 + mt * 16 + mq) * DD;
#pragma unroll
        for (int ks = 0; ks < 4; ++ks) {
            short8 a = *(const short8*)&arow[ks * 32 + quad * 8];
#pragma unroll
            for (int nt = 0; nt < 2; ++nt)
                acc[mt][nt] = __builtin_amdgcn_mfma_f32_16x16x32_bf16(
                    a, bfrag[nt][ks], acc[mt][nt], 0, 0, 0);
        }
    }

    // Epilogue. D: row = quad*4 + r, col = mq (per 16x16 tile).
    if (seg < 2) {
        ushort* hb = hrelb + (size_t)seg * NN * DD;
#pragma unroll
        for (int mt = 0; mt < 4; ++mt) {
#pragma unroll
            for (int r = 0; r < 4; ++r) {
                int node = node0 + mt * 16 + quad * 4 + r;
                if (node < NN) {
#pragma unroll
                    for (int nt = 0; nt < 2; ++nt)
                        hb[(size_t)node * DD + col0 + nt * 16 + mq] =
                            f2bf(acc[mt][nt][r]);
                }
            }
        }
    } else {
        float b0 = h_bias[col0 + mq];
        float b1 = h_bias[col0 + 16 + mq];
#pragma unroll
        for (int mt = 0; mt < 4; ++mt) {
#pragma unroll
            for (int r = 0; r < 4; ++r) {
                int node = node0 + mt * 16 + quad * 4 + r;
                if (node < NN) {
                    out[(size_t)node * DD + col0 + mq]      = acc[mt][0][r] + b0;
                    out[(size_t)node * DD + col0 + 16 + mq] = acc[mt][1][r] + b1;
                }
            }
        }
    }
}

// ---------------------------------------------------------------------------
// Fused exclusive scan of offs[0..OFFS_PAD) in ONE block (1024 threads,
// 49 rounds). Carry kept in registers (identical in all threads). Also
// writes cursor[i] = excl for i < NN.
// ---------------------------------------------------------------------------
__global__ __launch_bounds__(1024)
void scan_kernel(int* __restrict__ offs, int* __restrict__ cursor)
{
    __shared__ int ws[2][16];
    const int lane = threadIdx.x & 63;
    const int wvi  = threadIdx.x >> 6;
    int carry = 0;
    for (int r = 0; r < 49; ++r) {
        int i = r * 1024 + threadIdx.x;
        int v = offs[i];
        int inc = v;
#pragma unroll
        for (int d = 1; d < 64; d <<= 1) {
            int t = __shfl_up(inc, d, 64);
            if (lane >= d) inc += t;
        }
        if (lane == 63) ws[r & 1][wvi] = inc;
        __syncthreads();
        int wbase = 0, total = 0;
#pragma unroll
        for (int w = 0; w < 16; ++w) {
            int s = ws[r & 1][w];
            total += s;
            if (w < wvi) wbase += s;
        }
        int excl = carry + wbase + inc - v;
        offs[i] = excl;                 // i == NN gets total (=NE) ✓
        if (i < NN) cursor[i] = excl;
        carry += total;
    }
}

// payload[p] = ety*NN + src  → direct hrelb row index for gather.
__global__ __launch_bounds__(256)
void place_kernel(const int* __restrict__ src, const int* __restrict__ dst,
                  const int* __restrict__ ety,
                  int* __restrict__ cursor, int* __restrict__ payload)
{
    int e = blockIdx.x * 256 + threadIdx.x;
    if (e >= NE) return;
    int p = atomicAdd(&cursor[dst[e]], 1);
    payload[p] = ety[e] * NN + src[e];
}

// ---------------------------------------------------------------------------
// Gather: one wave per node; bf16 messages, fp32 accumulate, 4 loads in
// flight. acc starts at out[n] (= bias + loop message).
// ---------------------------------------------------------------------------
__global__ __launch_bounds__(256)
void gather_kernel(const int* __restrict__ offs, const int* __restrict__ payload,
                   const ushort* __restrict__ hrelb, float* __restrict__ out)
{
    const int n = blockIdx.x * 4 + (threadIdx.x >> 6);
    if (n >= NN) return;
    const int lane = threadIdx.x & 63;
    const int e0 = offs[n];
    const int e1 = offs[n + 1];
    float* orow = out + (size_t)n * DD;
    float2 a0 = ((float2*)orow)[lane];
    float2 a1 = make_float2(0.f, 0.f);
    float2 a2 = make_float2(0.f, 0.f);
    float2 a3 = make_float2(0.f, 0.f);
    int e = e0;
    for (; e + 4 <= e1; e += 4) {
        int p0 = payload[e],     p1 = payload[e + 1];
        int p2 = payload[e + 2], p3 = payload[e + 3];
        uint d0 = *(const uint*)&hrelb[(size_t)p0 * DD + lane * 2];
        uint d1 = *(const uint*)&hrelb[(size_t)p1 * DD + lane * 2];
        uint d2 = *(const uint*)&hrelb[(size_t)p2 * DD + lane * 2];
        uint d3 = *(const uint*)&hrelb[(size_t)p3 * DD + lane * 2];
        a0.x += bf_lo(d0); a0.y += bf_hi(d0);
        a1.x += bf_lo(d1); a1.y += bf_hi(d1);
        a2.x += bf_lo(d2); a2.y += bf_hi(d2);
        a3.x += bf_lo(d3); a3.y += bf_hi(d3);
    }
    for (; e < e1; ++e) {
        int p0 = payload[e];
        uint d0 = *(const uint*)&hrelb[(size_t)p0 * DD + lane * 2];
        a0.x += bf_lo(d0); a0.y += bf_hi(d0);
    }
    a0.x += a1.x + a2.x + a3.x;
    a0.y += a1.y + a2.y + a3.y;
    ((float2*)orow)[lane] = a0;
}

// ---------------------------------------------------------------------------
// Tier-2 fallback: atomic scatter from bf16 hrelb.
// ---------------------------------------------------------------------------
__global__ __launch_bounds__(256)
void scatter_kernel(const int* __restrict__ src, const int* __restrict__ dst,
                    const int* __restrict__ ety,
                    const ushort* __restrict__ hrelb,
                    float* __restrict__ out)
{
    const int e = blockIdx.x * 4 + (threadIdx.x >> 6);
    if (e >= NE) return;
    const int lane = threadIdx.x & 63;
    uint d0 = *(const uint*)&hrelb[
        ((size_t)ety[e] * NN + src[e]) * DD + lane * 2];
    float* o = out + (size_t)dst[e] * DD + lane * 2;
    atomicAdd(o,     bf_lo(d0));
    atomicAdd(o + 1, bf_hi(d0));
}

// Tier-3 fallback: fp32 out-init (loop message + bias) + fused per-edge matvec.
__global__ __launch_bounds__(256)
void loop_init_kernel(const float* __restrict__ feat,
                      const float* __restrict__ loop_weight,
                      const float* __restrict__ h_bias,
                      float* __restrict__ out)
{
    const int n = blockIdx.x * 4 + (threadIdx.x >> 6);
    if (n >= NN) return;
    const int lane = threadIdx.x & 63;
    const float2 fv = ((const float2*)(feat + (size_t)n * DD))[lane];
    float a0 = h_bias[lane], a1 = h_bias[lane + 64];
    for (int k = 0; k < 64; ++k) {
        float f0 = __shfl(fv.x, k, 64);
        float f1 = __shfl(fv.y, k, 64);
        a0 += SQ_A * (f0 * loop_weight[(size_t)(2 * k) * DD + lane]
                    + f1 * loop_weight[(size_t)(2 * k + 1) * DD + lane]);
        a1 += SQ_A * (f0 * loop_weight[(size_t)(2 * k) * DD + lane + 64]
                    + f1 * loop_weight[(size_t)(2 * k + 1) * DD + lane + 64]);
    }
    out[(size_t)n * DD + lane] = a0;
    out[(size_t)n * DD + lane + 64] = a1;
}

__global__ __launch_bounds__(256)
void fused_edge_kernel(const float* __restrict__ feat,
                       const int* __restrict__ src, const int* __restrict__ dst,
                       const int* __restrict__ ety,
                       const float* __restrict__ weight,
                       float* __restrict__ out)
{
    const int wave  = threadIdx.x >> 6;
    const int lane  = threadIdx.x & 63;
    const int nwav  = gridDim.x * 4;
    for (int e = blockIdx.x * 4 + wave; e < NE; e += nwav) {
        const int s = src[e];
        const int d = dst[e];
        const int r = ety[e];
        const float2 fv = ((const float2*)(feat + (size_t)s * DD))[lane];
        const float* W = weight + (size_t)r * DD * DD;
        float a0 = 0.f, a1 = 0.f;
        for (int k = 0; k < 64; ++k) {
            float f0 = __shfl(fv.x, k, 64);
            float f1 = __shfl(fv.y, k, 64);
            a0 += f0 * W[(size_t)(2 * k) * DD + lane]
                + f1 * W[(size_t)(2 * k + 1) * DD + lane];
            a1 += f0 * W[(size_t)(2 * k) * DD + lane + 64]
                + f1 * W[(size_t)(2 * k + 1) * DD + lane + 64];
        }
        atomicAdd(out + (size_t)d * DD + lane,      SQ_A * a0);
        atomicAdd(out + (size_t)d * DD + lane + 64, SQ_A * a1);
    }
}

extern "C" void kernel_launch(void* const* d_in, const int* in_sizes, int n_in,
                              void* d_out, int out_size, void* d_ws, size_t ws_size,
                              hipStream_t stream)
{
    const float* feat   = (const float*)d_in[0];
    const int*   src    = (const int*)d_in[1];
    const int*   dst    = (const int*)d_in[2];
    const int*   ety    = (const int*)d_in[3];
    const float* weight = (const float*)d_in[4];
    const float* loop_w = (const float*)d_in[5];
    const float* h_bias = (const float*)d_in[6];
    float* out  = (float*)d_out;

    // Workspace layout (all sections 16B-multiple sized).
    char* p = (char*)d_ws;
    ushort* featb = (ushort*)p;  p += (size_t)NPAD * DD * 2;    // 12.81 MB
    ushort* wtb   = (ushort*)p;  p += (size_t)3 * DD * DD * 2;  // 96 KB
    ushort* hrelb = (ushort*)p;  p += (size_t)2 * NN * DD * 2;  // 25.6 MB
    int* offs     = (int*)p;     p += (size_t)OFFS_PAD * 4;
    const size_t need_t2 = (size_t)(p - (char*)d_ws);
    int* cursor   = (int*)p;     p += (size_t)OFFS_PAD * 4;
    int* payload  = (int*)p;     p += (size_t)NE * 4;
    const size_t need_full = (size_t)(p - (char*)d_ws);         // ~41.2 MB

    if (ws_size >= need_full) {
        prep_kernel<<<(PREP_TASKS + 255) / 256, 256, 0, stream>>>(
            feat, weight, loop_w, featb, wtb, offs);
        transform_mfma_kernel<<<dim3(3, NTILE), 256, 0, stream>>>(
            featb, wtb, h_bias, dst, offs, hrelb, out);
        scan_kernel<<<1, 1024, 0, stream>>>(offs, cursor);
        place_kernel<<<(NE + 255) / 256, 256, 0, stream>>>(
            src, dst, ety, cursor, payload);
        gather_kernel<<<(NN + 3) / 4, 256, 0, stream>>>(
            offs, payload, hrelb, out);
    } else if (ws_size >= need_t2) {
        prep_kernel<<<(PREP_TASKS + 255) / 256, 256, 0, stream>>>(
            feat, weight, loop_w, featb, wtb, offs);
        transform_mfma_kernel<<<dim3(3, NTILE), 256, 0, stream>>>(
            featb, wtb, h_bias, dst, offs, hrelb, out);
        scatter_kernel<<<dim3((NE + 3) / 4), 256, 0, stream>>>(
            src, dst, ety, hrelb, out);
    } else {
        loop_init_kernel<<<(NN + 3) / 4, 256, 0, stream>>>(
            feat, loop_w, h_bias, out);
        fused_edge_kernel<<<dim3(2048), 256, 0, stream>>>(
            feat, src, dst, ety, weight, out);
    }
}